// Round 1
// 1612.866 us; speedup vs baseline: 1.3242x; 1.3242x over previous
//
#include <hip/hip_runtime.h>
#include <hip/hip_bf16.h>

typedef unsigned short u16;
typedef unsigned long long u64;

#define BB 32
#define HH 56
#define WW 56
#define CC 384
#define HEADS 12
#define WSZ 7
#define SHIFT 3
#define HD 32
#define NN 49
#define SCALE 0.17677669529663687f  // 1/sqrt(32)

#define NWIN_TOT 2048            // B * 64 windows
#define ROWS_TOT (BB * HH * WW)  // 100352

typedef __attribute__((ext_vector_type(8))) __bf16 v8bf;
typedef __attribute__((ext_vector_type(4))) float v4f;

__device__ __forceinline__ u16 f2bu(float f) {
    unsigned u = __float_as_uint(f);
    unsigned r = (u + 0x7fffu + ((u >> 16) & 1u)) >> 16;
    return (u16)r;
}
__device__ __forceinline__ float bu2f(u16 h) { return __uint_as_float(((unsigned)h) << 16); }

// ---------------------------------------------------------------------------
// Weight convert + transpose: in f32 (K x N) -> out bf16 (N x K)
// ---------------------------------------------------------------------------
__global__ __launch_bounds__(256) void cvtT_k(const float* __restrict__ in,
                                              u16* __restrict__ outb, int K, int N) {
    __shared__ float sh[32][33];
    int tx = threadIdx.x & 31, ty = threadIdx.x >> 5;  // 32 x 8
    int n0 = blockIdx.x * 32, k0 = blockIdx.y * 32;
#pragma unroll
    for (int r = 0; r < 4; r++) {
        int k = k0 + ty + 8 * r;
        sh[ty + 8 * r][tx] = in[(size_t)k * N + n0 + tx];
    }
    __syncthreads();
#pragma unroll
    for (int r = 0; r < 4; r++) {
        int n = n0 + ty + 8 * r;
        outb[(size_t)n * K + k0 + tx] = f2bu(sh[tx][ty + 8 * r]);
    }
}

// ---------------------------------------------------------------------------
// K0: precompute masked bias table: mbias[cls][h][n][m] (f32)
//     cls = (bottom?1:0) + (right?2:0)
// ---------------------------------------------------------------------------
__global__ __launch_bounds__(256) void mbias_k(const float* __restrict__ rpb,
                                               float* __restrict__ mbias) {
    int idx = blockIdx.x * 256 + threadIdx.x;
    if (idx >= 4 * HEADS * NN * NN) return;
    int m = idx % NN;
    int n = (idx / NN) % NN;
    int h = (idx / (NN * NN)) % HEADS;
    int cls = idx / (NN * NN * HEADS);
    int i1 = n / WSZ, j1 = n % WSZ, i2 = m / WSZ, j2 = m % WSZ;
    int ridx = (i1 - i2 + WSZ - 1) * (2 * WSZ - 1) + (j1 - j2 + WSZ - 1);
    float v = rpb[ridx * HEADS + h];
    int bot = cls & 1, rgt = (cls >> 1) & 1;
    int rh1 = bot ? ((i1 < 4) ? 1 : 2) : 0;
    int rh2 = bot ? ((i2 < 4) ? 1 : 2) : 0;
    int rw1 = rgt ? ((j1 < 4) ? 1 : 2) : 0;
    int rw2 = rgt ? ((j2 < 4) ? 1 : 2) : 0;
    if (rh1 != rh2 || rw1 != rw2) v -= 100.0f;
    mbias[idx] = v;
}

// ---------------------------------------------------------------------------
// K1: LN1 + cyclic shift(-3,-3) + window partition -> bf16 rows
// ---------------------------------------------------------------------------
__global__ __launch_bounds__(64) void ln_part_k(const float* __restrict__ x,
                                                const float* __restrict__ g,
                                                const float* __restrict__ bta,
                                                u16* __restrict__ out, int win_off) {
    int r = blockIdx.x;
    int lane = threadIdx.x;
    int wl = r / NN, n = r % NN;
    int wg = win_off + wl;
    int bi = wg >> 6;
    int w_ = wg & 63;
    int wh = w_ >> 3, wwi = w_ & 7;
    int i = n / WSZ, j = n % WSZ;
    int ho = (wh * WSZ + i + SHIFT) % HH;
    int wo = (wwi * WSZ + j + SHIFT) % WW;
    const float* src = x + ((size_t)bi * (HH * WW) + ho * WW + wo) * CC;

    float xv[6];
    float s = 0.f, s2 = 0.f;
#pragma unroll
    for (int k = 0; k < 6; k++) {
        float v = src[lane + k * 64];
        xv[k] = v; s += v; s2 += v * v;
    }
#pragma unroll
    for (int off = 32; off > 0; off >>= 1) {
        s += __shfl_down(s, off);
        s2 += __shfl_down(s2, off);
    }
    s = __shfl(s, 0); s2 = __shfl(s2, 0);
    float mean = s * (1.0f / CC);
    float var = s2 * (1.0f / CC) - mean * mean;
    float rstd = rsqrtf(var + 1e-5f);

    u16* dst = out + (size_t)r * CC;
#pragma unroll
    for (int k = 0; k < 6; k++) {
        int c = lane + k * 64;
        dst[c] = f2bu((xv[k] - mean) * rstd * g[c] + bta[c]);
    }
}

// ---------------------------------------------------------------------------
// K4: LN2 on residual stream -> bf16 rows
// ---------------------------------------------------------------------------
__global__ __launch_bounds__(64) void ln2_k(const float* __restrict__ xin,
                                            const float* __restrict__ g,
                                            const float* __restrict__ bta,
                                            u16* __restrict__ out, int row_off) {
    int r = blockIdx.x;
    int lane = threadIdx.x;
    const float* src = xin + (size_t)(row_off + r) * CC;
    float xv[6];
    float s = 0.f, s2 = 0.f;
#pragma unroll
    for (int k = 0; k < 6; k++) {
        float v = src[lane + k * 64];
        xv[k] = v; s += v; s2 += v * v;
    }
#pragma unroll
    for (int off = 32; off > 0; off >>= 1) {
        s += __shfl_down(s, off);
        s2 += __shfl_down(s2, off);
    }
    s = __shfl(s, 0); s2 = __shfl(s2, 0);
    float mean = s * (1.0f / CC);
    float var = s2 * (1.0f / CC) - mean * mean;
    float rstd = rsqrtf(var + 1e-5f);
    u16* dst = out + (size_t)r * CC;
#pragma unroll
    for (int k = 0; k < 6; k++) {
        int c = lane + k * 64;
        dst[c] = f2bu((xv[k] - mean) * rstd * g[c] + bta[c]);
    }
}

// ---------------------------------------------------------------------------
// K2: MFMA GEMM  C = A(MxK bf16) @ W^T(NxK bf16) + bias(f32)
// ---------------------------------------------------------------------------
#define LDK 40  // 32 + 8 pad (bf16 units); row stride 80B

template <int EPI>
__global__ __launch_bounds__(256) void mgemm_k(const u16* __restrict__ A,
                                               const u16* __restrict__ Bt,
                                               const float* __restrict__ bias,
                                               u16* __restrict__ outb,
                                               int M, int Nn, int K,
                                               const float* __restrict__ resid,
                                               float* __restrict__ dout, int off_idx) {
    __shared__ u16 As[128 * LDK];
    __shared__ u16 Bs[128 * LDK];
    int tid = threadIdx.x;
    int lane = tid & 63, wave = tid >> 6;
    int wy = (wave >> 1) * 64, wx = (wave & 1) * 64;
    int row0 = blockIdx.y * 128, col0 = blockIdx.x * 128;
    int mrow = lane & 15, kq = lane >> 4;

    v4f acc[4][4];
    v4f zz = {0.f, 0.f, 0.f, 0.f};
#pragma unroll
    for (int i = 0; i < 4; i++)
#pragma unroll
        for (int j = 0; j < 4; j++) acc[i][j] = zz;

    int m0 = tid >> 3;            // 0..31 (+32*r)
    int ksl = (tid & 7) * 4;      // 0,4,...,28
    const u16* Ab = A + (size_t)row0 * K;
    const u16* Bb = Bt + (size_t)col0 * K;

    for (int kt = 0; kt < K; kt += 32) {
#pragma unroll
        for (int r = 0; r < 4; r++) {
            int m = m0 + 32 * r;
            u64 av = *(const u64*)(Ab + (size_t)m * K + kt + ksl);
            u64 bv = *(const u64*)(Bb + (size_t)m * K + kt + ksl);
            *(u64*)(&As[m * LDK + ksl]) = av;
            *(u64*)(&Bs[m * LDK + ksl]) = bv;
        }
        __syncthreads();
        v8bf af[4], bfr[4];
#pragma unroll
        for (int i = 0; i < 4; i++) {
            af[i]  = *(const v8bf*)(&As[(wy + i * 16 + mrow) * LDK + 8 * kq]);
            bfr[i] = *(const v8bf*)(&Bs[(wx + i * 16 + mrow) * LDK + 8 * kq]);
        }
#pragma unroll
        for (int i = 0; i < 4; i++)
#pragma unroll
            for (int j = 0; j < 4; j++)
                acc[i][j] = __builtin_amdgcn_mfma_f32_16x16x32_bf16(af[i], bfr[j], acc[i][j], 0, 0, 0);
        __syncthreads();
    }

#pragma unroll
    for (int i = 0; i < 4; i++) {
#pragma unroll
        for (int j = 0; j < 4; j++) {
#pragma unroll
            for (int r = 0; r < 4; r++) {
                int row = row0 + wy + i * 16 + kq * 4 + r;
                int col = col0 + wx + j * 16 + mrow;
                float v = acc[i][j][r] + bias[col];
                if constexpr (EPI == 0) {
                    outb[(size_t)row * Nn + col] = f2bu(v);
                } else if constexpr (EPI == 1) {
                    v = 0.5f * v * (1.0f + erff(v * 0.70710678118f));
                    outb[(size_t)row * Nn + col] = f2bu(v);
                } else if constexpr (EPI == 2) {
                    int wl = row / NN, n = row % NN;
                    int wg = off_idx + wl;
                    int bi = wg >> 6, w_ = wg & 63;
                    int wh = w_ >> 3, wwi = w_ & 7;
                    int i1 = n / WSZ, j1 = n % WSZ;
                    int ho = (wh * WSZ + i1 + SHIFT) % HH;
                    int wo = (wwi * WSZ + j1 + SHIFT) % WW;
                    size_t gidx = ((size_t)bi * (HH * WW) + ho * WW + wo) * CC + col;
                    dout[gidx] = resid[gidx] + v;
                } else {  // EPI 3
                    size_t gidx = (size_t)(off_idx + row) * CC + col;
                    dout[gidx] = dout[gidx] + v;
                }
            }
        }
    }
}

// ---------------------------------------------------------------------------
// K3: MFMA attention. One wave per (window, head); 4 waves / block.
// Fragment convention identical to mgemm_k (harness-verified):
//   A-frag: lane(mrow,kq) holds row=mrow(+16i), k=8kq..8kq+7
//   D:      row = 4*kq+r (+16i), col = mrow (+16j)
// QK^T: A=Q rows, Bt=K rows, K-dim=HD=32 (one step), 64x64 padded (rows clamped).
// Softmax in D layout (shfl_xor over mrow lanes), P -> LDS bf16.
// PV:  A=P (rows n, k=m: 2 k-steps), Bt=V^T staged in LDS (rows d, k=m).
// ---------------------------------------------------------------------------
#define LDP 72  // P row stride (u16): 144B, 16B-aligned
#define LDV 72  // vT row stride (u16): 144B, 16B-aligned

__global__ __launch_bounds__(256) void attn_k(const u16* __restrict__ qkv,
                                              const float* __restrict__ mbias,
                                              u16* __restrict__ xa, int win_off) {
    __shared__ u16 PsA[4][NN * LDP];       // 4 x 7056B
    __shared__ u16 vTA[4][HD * LDV];       // 4 x 4608B
    int tid = threadIdx.x;
    int wv = tid >> 6, lane = tid & 63;
    int mrow = lane & 15, kq = lane >> 4;
    int gu = blockIdx.x * 4 + wv;          // (window,head) unit
    int h = gu % HEADS;
    int wl = gu / HEADS;
    int wg = win_off + wl;
    int w_ = wg & 63, wh = w_ >> 3, wwc = w_ & 7;
    int cls = ((wh == 7) ? 1 : 0) + ((wwc == 7) ? 2 : 0);
    u16* Ps = PsA[wv];
    u16* vT = vTA[wv];
    const u16* base = qkv + (size_t)wl * NN * (3 * CC) + h * HD;

    // ---- stage V^T into LDS: vT[d][m] = V[m][d]; m in [49,64) zero-padded ----
#pragma unroll
    for (int it = 0; it < 8; it++) {
        int idx = it * 256 + lane * 4;     // covers 64 m x 32 d
        int m = idx >> 5, d = idx & 31;    // d multiple of 4
        u64 v4 = 0;
        if (m < NN) v4 = *(const u64*)(base + (size_t)m * (3 * CC) + 2 * CC + d);
        vT[(d + 0) * LDV + m] = (u16)v4;
        vT[(d + 1) * LDV + m] = (u16)(v4 >> 16);
        vT[(d + 2) * LDV + m] = (u16)(v4 >> 32);
        vT[(d + 3) * LDV + m] = (u16)(v4 >> 48);
    }

    // ---- Q,K fragments direct from global (16B aligned), rows clamped ----
    v8bf aq[4], bk[4];
#pragma unroll
    for (int i = 0; i < 4; i++) {
        int n = 16 * i + mrow;
        if (n > 48) n = 48;
        const u16* rp = base + (size_t)n * (3 * CC) + 8 * kq;
        aq[i] = *(const v8bf*)(rp);        // Q row n, d=8kq..+7
        bk[i] = *(const v8bf*)(rp + CC);   // K row n, d=8kq..+7
    }

    v4f zz = {0.f, 0.f, 0.f, 0.f};
    v4f s[4][4];
#pragma unroll
    for (int i = 0; i < 4; i++)
#pragma unroll
        for (int j = 0; j < 4; j++) s[i][j] = zz;
#pragma unroll
    for (int i = 0; i < 4; i++)
#pragma unroll
        for (int j = 0; j < 4; j++)
            s[i][j] = __builtin_amdgcn_mfma_f32_16x16x32_bf16(aq[i], bk[j], s[i][j], 0, 0, 0);

    // ---- softmax (D layout): rows n = 16i+4kq+r, cols m = 16j+mrow ----
    const float* bb = mbias + ((size_t)cls * HEADS + h) * (NN * NN);
#pragma unroll
    for (int i = 0; i < 4; i++) {
#pragma unroll
        for (int r = 0; r < 4; r++) {
            int n = 16 * i + 4 * kq + r;
            if (n < NN) {                  // uniform across the 16-lane shfl group
                const float* br = bb + n * NN;
                float v[4];
#pragma unroll
                for (int j = 0; j < 4; j++) {
                    int m = 16 * j + mrow;
                    float t = s[i][j][r] * SCALE + br[(m > 48) ? 48 : m];
                    v[j] = (m < NN) ? t : -1e30f;
                }
                float mx = fmaxf(fmaxf(v[0], v[1]), fmaxf(v[2], v[3]));
#pragma unroll
                for (int off = 1; off < 16; off <<= 1) mx = fmaxf(mx, __shfl_xor(mx, off));
                float sum = 0.f;
#pragma unroll
                for (int j = 0; j < 4; j++) { v[j] = __expf(v[j] - mx); sum += v[j]; }
#pragma unroll
                for (int off = 1; off < 16; off <<= 1) sum += __shfl_xor(sum, off);
                float inv = 1.0f / sum;
#pragma unroll
                for (int j = 0; j < 4; j++)
                    Ps[n * LDP + 16 * j + mrow] = f2bu(v[j] * inv);
            }
        }
    }

    // ---- O = P @ V : K-dim 64 (2 steps); A rows clamped to 48 ----
    v4f o[4][2];
#pragma unroll
    for (int i = 0; i < 4; i++)
#pragma unroll
        for (int j = 0; j < 2; j++) o[i][j] = zz;
#pragma unroll
    for (int kt = 0; kt < 2; kt++) {
        v8bf ap[4], bv[2];
#pragma unroll
        for (int i = 0; i < 4; i++) {
            int pr = 16 * i + mrow;
            if (pr > 48) pr = 48;
            ap[i] = *(const v8bf*)(&Ps[pr * LDP + 8 * kq + 32 * kt]);
        }
#pragma unroll
        for (int j = 0; j < 2; j++)
            bv[j] = *(const v8bf*)(&vT[(16 * j + mrow) * LDV + 8 * kq + 32 * kt]);
#pragma unroll
        for (int i = 0; i < 4; i++)
#pragma unroll
            for (int j = 0; j < 2; j++)
                o[i][j] = __builtin_amdgcn_mfma_f32_16x16x32_bf16(ap[i], bv[j], o[i][j], 0, 0, 0);
    }

    // ---- write out: row n, col d = 16j+mrow ----
    u16* orow = xa + (size_t)wl * NN * CC + h * HD;
#pragma unroll
    for (int i = 0; i < 4; i++) {
#pragma unroll
        for (int r = 0; r < 4; r++) {
            int n = 16 * i + 4 * kq + r;
            if (n < NN) {
#pragma unroll
                for (int j = 0; j < 2; j++)
                    orow[(size_t)n * CC + 16 * j + mrow] = f2bu(o[i][j][r]);
            }
        }
    }
}

// ---------------------------------------------------------------------------
extern "C" void kernel_launch(void* const* d_in, const int* in_sizes, int n_in,
                              void* d_out, int out_size, void* d_ws, size_t ws_size,
                              hipStream_t stream) {
    const float* x     = (const float*)d_in[0];
    const float* ln1g  = (const float*)d_in[1];
    const float* ln1b  = (const float*)d_in[2];
    const float* qkvw  = (const float*)d_in[3];
    const float* qkvb  = (const float*)d_in[4];
    const float* rpb   = (const float*)d_in[5];
    const float* projw = (const float*)d_in[6];
    const float* projb = (const float*)d_in[7];
    const float* ln2g  = (const float*)d_in[8];
    const float* ln2b  = (const float*)d_in[9];
    const float* fc1w  = (const float*)d_in[10];
    const float* fc1b  = (const float*)d_in[11];
    const float* fc2w  = (const float*)d_in[12];
    const float* fc2b  = (const float*)d_in[13];
    float* out = (float*)d_out;
    char* ws = (char*)d_ws;

    // ---- weight regions (bf16, transposed to NxK) + mbias (f32) ----
    size_t o = 0;
    auto walloc = [&](size_t elems) { size_t c = o; o += ((elems * 2 + 1023) & ~(size_t)1023); return c; };
    size_t o_qkvT = walloc((size_t)1152 * 384);
    size_t o_projT = walloc((size_t)384 * 384);
    size_t o_fc1T = walloc((size_t)1536 * 384);
    size_t o_fc2T = walloc((size_t)384 * 1536);
    size_t o_mbias = o;
    o += (((size_t)4 * HEADS * NN * NN * sizeof(float)) + 1023) & ~(size_t)1023;
    size_t wgt_end = (o + 1023) & ~(size_t)1023;
    u16* qkvT = (u16*)(ws + o_qkvT);
    u16* projT = (u16*)(ws + o_projT);
    u16* fc1T = (u16*)(ws + o_fc1T);
    u16* fc2T = (u16*)(ws + o_fc2T);
    float* mbias = (float*)(ws + o_mbias);

    cvtT_k<<<dim3(1152 / 32, 384 / 32), dim3(256), 0, stream>>>(qkvw, qkvT, 384, 1152);
    cvtT_k<<<dim3(384 / 32, 384 / 32), dim3(256), 0, stream>>>(projw, projT, 384, 384);
    cvtT_k<<<dim3(1536 / 32, 384 / 32), dim3(256), 0, stream>>>(fc1w, fc1T, 384, 1536);
    cvtT_k<<<dim3(384 / 32, 1536 / 32), dim3(256), 0, stream>>>(fc2w, fc2T, 1536, 384);
    mbias_k<<<dim3((4 * HEADS * NN * NN + 255) / 256), dim3(256), 0, stream>>>(rpb, mbias);

    size_t avail = (ws_size > wgt_end) ? ws_size - wgt_end : 0;

    // ---- adaptive attention chunking (bf16 bufs): bufA (ln/xa) + bufB (qkv) ----
    int nca = 4;
    size_t offB_a = 0;
    for (; nca <= 16; nca *= 2) {
        int Wc = NWIN_TOT / nca;
        size_t a = (size_t)Wc * NN * CC * 2;
        a = (a + 1023) & ~(size_t)1023;
        size_t b = (size_t)Wc * NN * (3 * CC) * 2;
        if (a + b <= avail) { offB_a = a; break; }
    }
    if (nca > 16) { nca = 16; offB_a = (((size_t)(NWIN_TOT / 16) * NN * CC * 2) + 1023) & ~(size_t)1023; }
    int Wc = NWIN_TOT / nca;
    int Rw = Wc * NN;  // multiple of 128 for nca in {4,8,16}

    for (int c = 0; c < nca; c++) {
        int woff = c * Wc;
        u16* bufA = (u16*)(ws + wgt_end);
        u16* bufB = (u16*)(ws + wgt_end + offB_a);
        ln_part_k<<<dim3(Rw), dim3(64), 0, stream>>>(x, ln1g, ln1b, bufA, woff);
        mgemm_k<0><<<dim3(1152 / 128, Rw / 128), dim3(256), 0, stream>>>(
            bufA, qkvT, qkvb, bufB, Rw, 1152, 384, nullptr, nullptr, 0);
        attn_k<<<dim3(Wc * 3), dim3(256), 0, stream>>>(bufB, mbias, bufA, woff);
        mgemm_k<2><<<dim3(384 / 128, Rw / 128), dim3(256), 0, stream>>>(
            bufA, projT, projb, nullptr, Rw, 384, 384, x, out, woff);
    }

    // ---- adaptive MLP chunking: ln2-out (Rc x 384 bf16) + m1 (Rc x 1536 bf16) ----
    int ncm = 8;
    size_t offB_m = 0;
    for (; ncm <= 16; ncm *= 2) {
        int Rc = ROWS_TOT / ncm;
        size_t a = (size_t)Rc * CC * 2;
        a = (a + 1023) & ~(size_t)1023;
        size_t b = (size_t)Rc * (4 * CC) * 2;
        if (a + b <= avail) { offB_m = a; break; }
    }
    if (ncm > 16) { ncm = 16; offB_m = (((size_t)(ROWS_TOT / 16) * CC * 2) + 1023) & ~(size_t)1023; }
    int Rc = ROWS_TOT / ncm;

    for (int c = 0; c < ncm; c++) {
        int roff = c * Rc;
        u16* bufA = (u16*)(ws + wgt_end);
        u16* bufB = (u16*)(ws + wgt_end + offB_m);
        ln2_k<<<dim3(Rc), dim3(64), 0, stream>>>(out, ln2g, ln2b, bufA, roff);
        mgemm_k<1><<<dim3(1536 / 128, Rc / 128), dim3(256), 0, stream>>>(
            bufA, fc1T, fc1b, bufB, Rc, 1536, 384, nullptr, nullptr, 0);
        mgemm_k<3><<<dim3(384 / 128, Rc / 128), dim3(256), 0, stream>>>(
            bufB, fc2T, fc2b, nullptr, Rc, 384, 1536, nullptr, out, roff);
    }
}

// Round 2
// 1221.523 us; speedup vs baseline: 1.7484x; 1.3204x over previous
//
#include <hip/hip_runtime.h>
#include <hip/hip_bf16.h>

typedef unsigned short u16;
typedef unsigned long long u64;

#define BB 32
#define HH 56
#define WW 56
#define CC 384
#define HEADS 12
#define WSZ 7
#define SHIFT 3
#define HD 32
#define NN 49
#define SCALE 0.17677669529663687f  // 1/sqrt(32)

#define NWIN_TOT 2048            // B * 64 windows
#define ROWS_TOT (BB * HH * WW)  // 100352

typedef __attribute__((ext_vector_type(8))) __bf16 v8bf;
typedef __attribute__((ext_vector_type(4))) float v4f;

__device__ __forceinline__ u16 f2bu(float f) {
    unsigned u = __float_as_uint(f);
    unsigned r = (u + 0x7fffu + ((u >> 16) & 1u)) >> 16;
    return (u16)r;
}
__device__ __forceinline__ float bu2f(u16 h) { return __uint_as_float(((unsigned)h) << 16); }

__device__ __forceinline__ void gload_lds16(const u16* g, u16* l) {
    __builtin_amdgcn_global_load_lds(
        (const __attribute__((address_space(1))) void*)g,
        (__attribute__((address_space(3))) void*)l, 16, 0, 0);
}

// ---------------------------------------------------------------------------
// Weight convert + transpose: in f32 (K x N) -> out bf16 (N x K)
// ---------------------------------------------------------------------------
__global__ __launch_bounds__(256) void cvtT_k(const float* __restrict__ in,
                                              u16* __restrict__ outb, int K, int N) {
    __shared__ float sh[32][33];
    int tx = threadIdx.x & 31, ty = threadIdx.x >> 5;  // 32 x 8
    int n0 = blockIdx.x * 32, k0 = blockIdx.y * 32;
#pragma unroll
    for (int r = 0; r < 4; r++) {
        int k = k0 + ty + 8 * r;
        sh[ty + 8 * r][tx] = in[(size_t)k * N + n0 + tx];
    }
    __syncthreads();
#pragma unroll
    for (int r = 0; r < 4; r++) {
        int n = n0 + ty + 8 * r;
        outb[(size_t)n * K + k0 + tx] = f2bu(sh[tx][ty + 8 * r]);
    }
}

// ---------------------------------------------------------------------------
// K0: precompute masked bias table: mbias[cls][h][n][m] (f32)
// ---------------------------------------------------------------------------
__global__ __launch_bounds__(256) void mbias_k(const float* __restrict__ rpb,
                                               float* __restrict__ mbias) {
    int idx = blockIdx.x * 256 + threadIdx.x;
    if (idx >= 4 * HEADS * NN * NN) return;
    int m = idx % NN;
    int n = (idx / NN) % NN;
    int h = (idx / (NN * NN)) % HEADS;
    int cls = idx / (NN * NN * HEADS);
    int i1 = n / WSZ, j1 = n % WSZ, i2 = m / WSZ, j2 = m % WSZ;
    int ridx = (i1 - i2 + WSZ - 1) * (2 * WSZ - 1) + (j1 - j2 + WSZ - 1);
    float v = rpb[ridx * HEADS + h];
    int bot = cls & 1, rgt = (cls >> 1) & 1;
    int rh1 = bot ? ((i1 < 4) ? 1 : 2) : 0;
    int rh2 = bot ? ((i2 < 4) ? 1 : 2) : 0;
    int rw1 = rgt ? ((j1 < 4) ? 1 : 2) : 0;
    int rw2 = rgt ? ((j2 < 4) ? 1 : 2) : 0;
    if (rh1 != rh2 || rw1 != rw2) v -= 100.0f;
    mbias[idx] = v;
}

// ---------------------------------------------------------------------------
// K1: LN1 + cyclic shift(-3,-3) + window partition -> bf16 rows
// ---------------------------------------------------------------------------
__global__ __launch_bounds__(64) void ln_part_k(const float* __restrict__ x,
                                                const float* __restrict__ g,
                                                const float* __restrict__ bta,
                                                u16* __restrict__ out, int win_off) {
    int r = blockIdx.x;
    int lane = threadIdx.x;
    int wl = r / NN, n = r % NN;
    int wg = win_off + wl;
    int bi = wg >> 6;
    int w_ = wg & 63;
    int wh = w_ >> 3, wwi = w_ & 7;
    int i = n / WSZ, j = n % WSZ;
    int ho = (wh * WSZ + i + SHIFT) % HH;
    int wo = (wwi * WSZ + j + SHIFT) % WW;
    const float* src = x + ((size_t)bi * (HH * WW) + ho * WW + wo) * CC;

    float xv[6];
    float s = 0.f, s2 = 0.f;
#pragma unroll
    for (int k = 0; k < 6; k++) {
        float v = src[lane + k * 64];
        xv[k] = v; s += v; s2 += v * v;
    }
#pragma unroll
    for (int off = 32; off > 0; off >>= 1) {
        s += __shfl_down(s, off);
        s2 += __shfl_down(s2, off);
    }
    s = __shfl(s, 0); s2 = __shfl(s2, 0);
    float mean = s * (1.0f / CC);
    float var = s2 * (1.0f / CC) - mean * mean;
    float rstd = rsqrtf(var + 1e-5f);

    u16* dst = out + (size_t)r * CC;
#pragma unroll
    for (int k = 0; k < 6; k++) {
        int c = lane + k * 64;
        dst[c] = f2bu((xv[k] - mean) * rstd * g[c] + bta[c]);
    }
}

// ---------------------------------------------------------------------------
// K4: LN2 on residual stream -> bf16 rows
// ---------------------------------------------------------------------------
__global__ __launch_bounds__(64) void ln2_k(const float* __restrict__ xin,
                                            const float* __restrict__ g,
                                            const float* __restrict__ bta,
                                            u16* __restrict__ out, int row_off) {
    int r = blockIdx.x;
    int lane = threadIdx.x;
    const float* src = xin + (size_t)(row_off + r) * CC;
    float xv[6];
    float s = 0.f, s2 = 0.f;
#pragma unroll
    for (int k = 0; k < 6; k++) {
        float v = src[lane + k * 64];
        xv[k] = v; s += v; s2 += v * v;
    }
#pragma unroll
    for (int off = 32; off > 0; off >>= 1) {
        s += __shfl_down(s, off);
        s2 += __shfl_down(s2, off);
    }
    s = __shfl(s, 0); s2 = __shfl(s2, 0);
    float mean = s * (1.0f / CC);
    float var = s2 * (1.0f / CC) - mean * mean;
    float rstd = rsqrtf(var + 1e-5f);
    u16* dst = out + (size_t)r * CC;
#pragma unroll
    for (int k = 0; k < 6; k++) {
        int c = lane + k * 64;
        dst[c] = f2bu((xv[k] - mean) * rstd * g[c] + bta[c]);
    }
}

// ---------------------------------------------------------------------------
// K2: MFMA GEMM  C = A(MxK bf16) @ W^T(NxK bf16) + bias(f32)
// 128x128 tile, BK=32, 256 thr = 4 waves.
// Staging: global_load_lds 16B, linear LDS [128][32], XOR-swizzled 16B units:
//   unit(row,kq) = row*4 + (kq ^ ((row>>1)&3))   (same involution on both sides)
// Read bank check: 16 consecutive rows at fixed kq spread over all 8
// bank-groups exactly 2x -> conflict-free.
// ---------------------------------------------------------------------------
template <int EPI>
__global__ __launch_bounds__(256) void mgemm_k(const u16* __restrict__ A,
                                               const u16* __restrict__ Bt,
                                               const float* __restrict__ bias,
                                               u16* __restrict__ outb,
                                               int M, int Nn, int K,
                                               const float* __restrict__ resid,
                                               float* __restrict__ dout, int off_idx) {
    __shared__ u16 As[128 * 32];
    __shared__ u16 Bs[128 * 32];
    int tid = threadIdx.x;
    int lane = tid & 63, wave = tid >> 6;
    int wy = (wave >> 1) * 64, wx = (wave & 1) * 64;
    int row0 = blockIdx.y * 128, col0 = blockIdx.x * 128;
    int mrow = lane & 15, kq = lane >> 4;

    v4f acc[4][4];
    v4f zz = {0.f, 0.f, 0.f, 0.f};
#pragma unroll
    for (int i = 0; i < 4; i++)
#pragma unroll
        for (int j = 0; j < 4; j++) acc[i][j] = zz;

    const u16* Ab = A + (size_t)row0 * K;
    const u16* Bb = Bt + (size_t)col0 * K;

    // ---- staging precompute: 2 issues of A + 2 of B per thread per k-step ----
    int u0 = wave * 128 + lane;        // unit 0..511 (each unit = 16B)
    int u1 = u0 + 64;
    int r0 = u0 >> 2, r1 = u1 >> 2;
    int k0s = (u0 & 3) ^ ((r0 >> 1) & 3);
    int k1s = (u1 & 3) ^ ((r1 >> 1) & 3);
    const u16* gA0 = Ab + (size_t)r0 * K + 8 * k0s;
    const u16* gA1 = Ab + (size_t)r1 * K + 8 * k1s;
    const u16* gB0 = Bb + (size_t)r0 * K + 8 * k0s;
    const u16* gB1 = Bb + (size_t)r1 * K + 8 * k1s;
    u16* lA0 = &As[(size_t)wave * 1024];            // units [wave*128, +64)
    u16* lA1 = &As[(size_t)wave * 1024 + 512];      // units [wave*128+64, +64)
    u16* lB0 = &Bs[(size_t)wave * 1024];
    u16* lB1 = &Bs[(size_t)wave * 1024 + 512];

    // ---- read-side swizzled offsets (loop-invariant) ----
    int offA[4], offB[4];
#pragma unroll
    for (int i = 0; i < 4; i++) {
        int ra = wy + i * 16 + mrow;
        int rb = wx + i * 16 + mrow;
        offA[i] = (ra * 4 + (kq ^ ((ra >> 1) & 3))) * 8;
        offB[i] = (rb * 4 + (kq ^ ((rb >> 1) & 3))) * 8;
    }

    for (int kt = 0; kt < K; kt += 32) {
        gload_lds16(gA0, lA0);
        gload_lds16(gA1, lA1);
        gload_lds16(gB0, lB0);
        gload_lds16(gB1, lB1);
        gA0 += 32; gA1 += 32; gB0 += 32; gB1 += 32;
        __syncthreads();
        v8bf af[4], bfr[4];
#pragma unroll
        for (int i = 0; i < 4; i++) {
            af[i]  = *(const v8bf*)(&As[offA[i]]);
            bfr[i] = *(const v8bf*)(&Bs[offB[i]]);
        }
#pragma unroll
        for (int i = 0; i < 4; i++)
#pragma unroll
            for (int j = 0; j < 4; j++)
                acc[i][j] = __builtin_amdgcn_mfma_f32_16x16x32_bf16(af[i], bfr[j], acc[i][j], 0, 0, 0);
        __syncthreads();
    }

#pragma unroll
    for (int i = 0; i < 4; i++) {
#pragma unroll
        for (int j = 0; j < 4; j++) {
#pragma unroll
            for (int r = 0; r < 4; r++) {
                int row = row0 + wy + i * 16 + kq * 4 + r;
                int col = col0 + wx + j * 16 + mrow;
                float v = acc[i][j][r] + bias[col];
                if constexpr (EPI == 0) {
                    outb[(size_t)row * Nn + col] = f2bu(v);
                } else if constexpr (EPI == 1) {
                    v = 0.5f * v * (1.0f + erff(v * 0.70710678118f));
                    outb[(size_t)row * Nn + col] = f2bu(v);
                } else if constexpr (EPI == 2) {
                    int wl = row / NN, n = row % NN;
                    int wg = off_idx + wl;
                    int bi = wg >> 6, w_ = wg & 63;
                    int wh = w_ >> 3, wwi = w_ & 7;
                    int i1 = n / WSZ, j1 = n % WSZ;
                    int ho = (wh * WSZ + i1 + SHIFT) % HH;
                    int wo = (wwi * WSZ + j1 + SHIFT) % WW;
                    size_t gidx = ((size_t)bi * (HH * WW) + ho * WW + wo) * CC + col;
                    dout[gidx] = resid[gidx] + v;
                } else {  // EPI 3
                    size_t gidx = (size_t)(off_idx + row) * CC + col;
                    dout[gidx] = dout[gidx] + v;
                }
            }
        }
    }
}

// ---------------------------------------------------------------------------
// K3: MFMA attention. One wave per (window, head); 4 waves / block.
// ---------------------------------------------------------------------------
#define LDP 72  // P row stride (u16): 144B, 16B-aligned
#define LDV 72  // vT row stride (u16): 144B, 16B-aligned

__global__ __launch_bounds__(256) void attn_k(const u16* __restrict__ qkv,
                                              const float* __restrict__ mbias,
                                              u16* __restrict__ xa, int win_off) {
    __shared__ u16 PsA[4][NN * LDP];       // 4 x 7056B
    __shared__ u16 vTA[4][HD * LDV];       // 4 x 4608B
    int tid = threadIdx.x;
    int wv = tid >> 6, lane = tid & 63;
    int mrow = lane & 15, kq = lane >> 4;
    int gu = blockIdx.x * 4 + wv;          // (window,head) unit
    int h = gu % HEADS;
    int wl = gu / HEADS;
    int wg = win_off + wl;
    int w_ = wg & 63, wh = w_ >> 3, wwc = w_ & 7;
    int cls = ((wh == 7) ? 1 : 0) + ((wwc == 7) ? 2 : 0);
    u16* Ps = PsA[wv];
    u16* vT = vTA[wv];
    const u16* base = qkv + (size_t)wl * NN * (3 * CC) + h * HD;

    // ---- stage V^T into LDS: vT[d][m] = V[m][d]; m in [49,64) zero-padded ----
#pragma unroll
    for (int it = 0; it < 8; it++) {
        int idx = it * 256 + lane * 4;     // covers 64 m x 32 d
        int m = idx >> 5, d = idx & 31;    // d multiple of 4
        u64 v4 = 0;
        if (m < NN) v4 = *(const u64*)(base + (size_t)m * (3 * CC) + 2 * CC + d);
        vT[(d + 0) * LDV + m] = (u16)v4;
        vT[(d + 1) * LDV + m] = (u16)(v4 >> 16);
        vT[(d + 2) * LDV + m] = (u16)(v4 >> 32);
        vT[(d + 3) * LDV + m] = (u16)(v4 >> 48);
    }

    // ---- Q,K fragments direct from global (16B aligned), rows clamped ----
    v8bf aq[4], bk[4];
#pragma unroll
    for (int i = 0; i < 4; i++) {
        int n = 16 * i + mrow;
        if (n > 48) n = 48;
        const u16* rp = base + (size_t)n * (3 * CC) + 8 * kq;
        aq[i] = *(const v8bf*)(rp);        // Q row n, d=8kq..+7
        bk[i] = *(const v8bf*)(rp + CC);   // K row n, d=8kq..+7
    }

    v4f zz = {0.f, 0.f, 0.f, 0.f};
    v4f s[4][4];
#pragma unroll
    for (int i = 0; i < 4; i++)
#pragma unroll
        for (int j = 0; j < 4; j++) s[i][j] = zz;
#pragma unroll
    for (int i = 0; i < 4; i++)
#pragma unroll
        for (int j = 0; j < 4; j++)
            s[i][j] = __builtin_amdgcn_mfma_f32_16x16x32_bf16(aq[i], bk[j], s[i][j], 0, 0, 0);

    // ---- softmax (D layout): rows n = 16i+4kq+r, cols m = 16j+mrow ----
    const float* bb = mbias + ((size_t)cls * HEADS + h) * (NN * NN);
#pragma unroll
    for (int i = 0; i < 4; i++) {
#pragma unroll
        for (int r = 0; r < 4; r++) {
            int n = 16 * i + 4 * kq + r;
            if (n < NN) {                  // uniform across the 16-lane shfl group
                const float* br = bb + n * NN;
                float v[4];
#pragma unroll
                for (int j = 0; j < 4; j++) {
                    int m = 16 * j + mrow;
                    float t = s[i][j][r] * SCALE + br[(m > 48) ? 48 : m];
                    v[j] = (m < NN) ? t : -1e30f;
                }
                float mx = fmaxf(fmaxf(v[0], v[1]), fmaxf(v[2], v[3]));
#pragma unroll
                for (int off = 1; off < 16; off <<= 1) mx = fmaxf(mx, __shfl_xor(mx, off));
                float sum = 0.f;
#pragma unroll
                for (int j = 0; j < 4; j++) { v[j] = __expf(v[j] - mx); sum += v[j]; }
#pragma unroll
                for (int off = 1; off < 16; off <<= 1) sum += __shfl_xor(sum, off);
                float inv = 1.0f / sum;
#pragma unroll
                for (int j = 0; j < 4; j++)
                    Ps[n * LDP + 16 * j + mrow] = f2bu(v[j] * inv);
            }
        }
    }

    // ---- O = P @ V : K-dim 64 (2 steps); A rows clamped to 48 ----
    v4f o[4][2];
#pragma unroll
    for (int i = 0; i < 4; i++)
#pragma unroll
        for (int j = 0; j < 2; j++) o[i][j] = zz;
#pragma unroll
    for (int kt = 0; kt < 2; kt++) {
        v8bf ap[4], bv[2];
#pragma unroll
        for (int i = 0; i < 4; i++) {
            int pr = 16 * i + mrow;
            if (pr > 48) pr = 48;
            ap[i] = *(const v8bf*)(&Ps[pr * LDP + 8 * kq + 32 * kt]);
        }
#pragma unroll
        for (int j = 0; j < 2; j++)
            bv[j] = *(const v8bf*)(&vT[(16 * j + mrow) * LDV + 8 * kq + 32 * kt]);
#pragma unroll
        for (int i = 0; i < 4; i++)
#pragma unroll
            for (int j = 0; j < 2; j++)
                o[i][j] = __builtin_amdgcn_mfma_f32_16x16x32_bf16(ap[i], bv[j], o[i][j], 0, 0, 0);
    }

    // ---- write out: row n, col d = 16j+mrow ----
    u16* orow = xa + (size_t)wl * NN * CC + h * HD;
#pragma unroll
    for (int i = 0; i < 4; i++) {
#pragma unroll
        for (int r = 0; r < 4; r++) {
            int n = 16 * i + 4 * kq + r;
            if (n < NN) {
#pragma unroll
                for (int j = 0; j < 2; j++)
                    orow[(size_t)n * CC + 16 * j + mrow] = f2bu(o[i][j][r]);
            }
        }
    }
}

// ---------------------------------------------------------------------------
extern "C" void kernel_launch(void* const* d_in, const int* in_sizes, int n_in,
                              void* d_out, int out_size, void* d_ws, size_t ws_size,
                              hipStream_t stream) {
    const float* x     = (const float*)d_in[0];
    const float* ln1g  = (const float*)d_in[1];
    const float* ln1b  = (const float*)d_in[2];
    const float* qkvw  = (const float*)d_in[3];
    const float* qkvb  = (const float*)d_in[4];
    const float* rpb   = (const float*)d_in[5];
    const float* projw = (const float*)d_in[6];
    const float* projb = (const float*)d_in[7];
    const float* ln2g  = (const float*)d_in[8];
    const float* ln2b  = (const float*)d_in[9];
    const float* fc1w  = (const float*)d_in[10];
    const float* fc1b  = (const float*)d_in[11];
    const float* fc2w  = (const float*)d_in[12];
    const float* fc2b  = (const float*)d_in[13];
    float* out = (float*)d_out;
    char* ws = (char*)d_ws;

    // ---- weight regions (bf16, transposed to NxK) + mbias (f32) ----
    size_t o = 0;
    auto walloc = [&](size_t elems) { size_t c = o; o += ((elems * 2 + 1023) & ~(size_t)1023); return c; };
    size_t o_qkvT = walloc((size_t)1152 * 384);
    size_t o_projT = walloc((size_t)384 * 384);
    size_t o_fc1T = walloc((size_t)1536 * 384);
    size_t o_fc2T = walloc((size_t)384 * 1536);
    size_t o_mbias = o;
    o += (((size_t)4 * HEADS * NN * NN * sizeof(float)) + 1023) & ~(size_t)1023;
    size_t wgt_end = (o + 1023) & ~(size_t)1023;
    u16* qkvT = (u16*)(ws + o_qkvT);
    u16* projT = (u16*)(ws + o_projT);
    u16* fc1T = (u16*)(ws + o_fc1T);
    u16* fc2T = (u16*)(ws + o_fc2T);
    float* mbias = (float*)(ws + o_mbias);

    cvtT_k<<<dim3(1152 / 32, 384 / 32), dim3(256), 0, stream>>>(qkvw, qkvT, 384, 1152);
    cvtT_k<<<dim3(384 / 32, 384 / 32), dim3(256), 0, stream>>>(projw, projT, 384, 384);
    cvtT_k<<<dim3(1536 / 32, 384 / 32), dim3(256), 0, stream>>>(fc1w, fc1T, 384, 1536);
    cvtT_k<<<dim3(384 / 32, 1536 / 32), dim3(256), 0, stream>>>(fc2w, fc2T, 1536, 384);
    mbias_k<<<dim3((4 * HEADS * NN * NN + 255) / 256), dim3(256), 0, stream>>>(rpb, mbias);

    size_t avail = (ws_size > wgt_end) ? ws_size - wgt_end : 0;

    // ---- adaptive attention chunking (bf16 bufs): bufA (ln/xa) + bufB (qkv) ----
    int nca = 1;
    size_t offB_a = 0;
    for (; nca <= 16; nca *= 2) {
        int Wc = NWIN_TOT / nca;
        size_t a = (size_t)Wc * NN * CC * 2;
        a = (a + 1023) & ~(size_t)1023;
        size_t b = (size_t)Wc * NN * (3 * CC) * 2;
        if (a + b <= avail) { offB_a = a; break; }
    }
    if (nca > 16) { nca = 16; offB_a = (((size_t)(NWIN_TOT / 16) * NN * CC * 2) + 1023) & ~(size_t)1023; }
    int Wc = NWIN_TOT / nca;
    int Rw = Wc * NN;  // multiple of 128 for nca in {1,2,4,8,16}

    for (int c = 0; c < nca; c++) {
        int woff = c * Wc;
        u16* bufA = (u16*)(ws + wgt_end);
        u16* bufB = (u16*)(ws + wgt_end + offB_a);
        ln_part_k<<<dim3(Rw), dim3(64), 0, stream>>>(x, ln1g, ln1b, bufA, woff);
        mgemm_k<0><<<dim3(1152 / 128, Rw / 128), dim3(256), 0, stream>>>(
            bufA, qkvT, qkvb, bufB, Rw, 1152, 384, nullptr, nullptr, 0);
        attn_k<<<dim3(Wc * 3), dim3(256), 0, stream>>>(bufB, mbias, bufA, woff);
        mgemm_k<2><<<dim3(384 / 128, Rw / 128), dim3(256), 0, stream>>>(
            bufA, projT, projb, nullptr, Rw, 384, 384, x, out, woff);
    }

    // ---- adaptive MLP chunking: ln2-out (Rc x 384 bf16) + m1 (Rc x 1536 bf16) ----
    int ncm = 1;
    size_t offB_m = 0;
    for (; ncm <= 16; ncm *= 2) {
        int Rc = ROWS_TOT / ncm;
        size_t a = (size_t)Rc * CC * 2;
        a = (a + 1023) & ~(size_t)1023;
        size_t b = (size_t)Rc * (4 * CC) * 2;
        if (a + b <= avail) { offB_m = a; break; }
    }
    if (ncm > 16) { ncm = 16; offB_m = (((size_t)(ROWS_TOT / 16) * CC * 2) + 1023) & ~(size_t)1023; }
    int Rc = ROWS_TOT / ncm;

    for (int c = 0; c < ncm; c++) {
        int roff = c * Rc;
        u16* bufA = (u16*)(ws + wgt_end);
        u16* bufB = (u16*)(ws + wgt_end + offB_m);
        ln2_k<<<dim3(Rc), dim3(64), 0, stream>>>(out, ln2g, ln2b, bufA, roff);
        mgemm_k<1><<<dim3(1536 / 128, Rc / 128), dim3(256), 0, stream>>>(
            bufA, fc1T, fc1b, bufB, Rc, 1536, 384, nullptr, nullptr, 0);
        mgemm_k<3><<<dim3(384 / 128, Rc / 128), dim3(256), 0, stream>>>(
            bufB, fc2T, fc2b, nullptr, Rc, 384, 1536, nullptr, out, roff);
    }
}

// Round 3
// 1140.101 us; speedup vs baseline: 1.8732x; 1.0714x over previous
//
#include <hip/hip_runtime.h>
#include <hip/hip_bf16.h>

typedef unsigned short u16;
typedef unsigned long long u64;

#define BB 32
#define HH 56
#define WW 56
#define CC 384
#define HEADS 12
#define WSZ 7
#define SHIFT 3
#define HD 32
#define NN 49
#define SCALE 0.17677669529663687f  // 1/sqrt(32)

#define NWIN_TOT 2048            // B * 64 windows
#define ROWS_TOT (BB * HH * WW)  // 100352

typedef __attribute__((ext_vector_type(8))) __bf16 v8bf;
typedef __attribute__((ext_vector_type(4))) float v4f;

__device__ __forceinline__ u16 f2bu(float f) {
    unsigned u = __float_as_uint(f);
    unsigned r = (u + 0x7fffu + ((u >> 16) & 1u)) >> 16;
    return (u16)r;
}
__device__ __forceinline__ float bu2f(u16 h) { return __uint_as_float(((unsigned)h) << 16); }

__device__ __forceinline__ void gload_lds16(const u16* g, u16* l) {
    __builtin_amdgcn_global_load_lds(
        (const __attribute__((address_space(1))) void*)g,
        (__attribute__((address_space(3))) void*)l, 16, 0, 0);
}

// Branch-free exact-GELU via A&S 7.1.26 erf approx (|err| <= 1.5e-7).
// ~16 VALU ops vs ~45 for libm erff with divergent branches.
__device__ __forceinline__ float gelu_f(float x) {
    float z = fabsf(x) * 0.70710678118654752f;
    float t = __builtin_amdgcn_rcpf(__builtin_fmaf(0.3275911f, z, 1.0f));
    float p = __builtin_fmaf(t, 1.061405429f, -1.453152027f);
    p = __builtin_fmaf(t, p, 1.421413741f);
    p = __builtin_fmaf(t, p, -0.284496736f);
    p = __builtin_fmaf(t, p, 0.254829592f);
    p = p * t;
    float e = __expf(-z * z);
    float erfv = 1.0f - p * e;                       // erf(|x|/sqrt2)
    float phi = 0.5f * (1.0f + copysignf(erfv, x));  // Phi(x)
    return x * phi;
}

// ---------------------------------------------------------------------------
// Weight convert + transpose: in f32 (K x N) -> out bf16 (N x K)
// ---------------------------------------------------------------------------
__global__ __launch_bounds__(256) void cvtT_k(const float* __restrict__ in,
                                              u16* __restrict__ outb, int K, int N) {
    __shared__ float sh[32][33];
    int tx = threadIdx.x & 31, ty = threadIdx.x >> 5;  // 32 x 8
    int n0 = blockIdx.x * 32, k0 = blockIdx.y * 32;
#pragma unroll
    for (int r = 0; r < 4; r++) {
        int k = k0 + ty + 8 * r;
        sh[ty + 8 * r][tx] = in[(size_t)k * N + n0 + tx];
    }
    __syncthreads();
#pragma unroll
    for (int r = 0; r < 4; r++) {
        int n = n0 + ty + 8 * r;
        outb[(size_t)n * K + k0 + tx] = f2bu(sh[tx][ty + 8 * r]);
    }
}

// ---------------------------------------------------------------------------
// K0: precompute masked bias table: mbias[cls][h][n][m] (f32)
// ---------------------------------------------------------------------------
__global__ __launch_bounds__(256) void mbias_k(const float* __restrict__ rpb,
                                               float* __restrict__ mbias) {
    int idx = blockIdx.x * 256 + threadIdx.x;
    if (idx >= 4 * HEADS * NN * NN) return;
    int m = idx % NN;
    int n = (idx / NN) % NN;
    int h = (idx / (NN * NN)) % HEADS;
    int cls = idx / (NN * NN * HEADS);
    int i1 = n / WSZ, j1 = n % WSZ, i2 = m / WSZ, j2 = m % WSZ;
    int ridx = (i1 - i2 + WSZ - 1) * (2 * WSZ - 1) + (j1 - j2 + WSZ - 1);
    float v = rpb[ridx * HEADS + h];
    int bot = cls & 1, rgt = (cls >> 1) & 1;
    int rh1 = bot ? ((i1 < 4) ? 1 : 2) : 0;
    int rh2 = bot ? ((i2 < 4) ? 1 : 2) : 0;
    int rw1 = rgt ? ((j1 < 4) ? 1 : 2) : 0;
    int rw2 = rgt ? ((j2 < 4) ? 1 : 2) : 0;
    if (rh1 != rh2 || rw1 != rw2) v -= 100.0f;
    mbias[idx] = v;
}

// ---------------------------------------------------------------------------
// K1: LN1 + cyclic shift(-3,-3) + window partition -> bf16 rows
// ---------------------------------------------------------------------------
__global__ __launch_bounds__(64) void ln_part_k(const float* __restrict__ x,
                                                const float* __restrict__ g,
                                                const float* __restrict__ bta,
                                                u16* __restrict__ out, int win_off) {
    int r = blockIdx.x;
    int lane = threadIdx.x;
    int wl = r / NN, n = r % NN;
    int wg = win_off + wl;
    int bi = wg >> 6;
    int w_ = wg & 63;
    int wh = w_ >> 3, wwi = w_ & 7;
    int i = n / WSZ, j = n % WSZ;
    int ho = (wh * WSZ + i + SHIFT) % HH;
    int wo = (wwi * WSZ + j + SHIFT) % WW;
    const float* src = x + ((size_t)bi * (HH * WW) + ho * WW + wo) * CC;

    float xv[6];
    float s = 0.f, s2 = 0.f;
#pragma unroll
    for (int k = 0; k < 6; k++) {
        float v = src[lane + k * 64];
        xv[k] = v; s += v; s2 += v * v;
    }
#pragma unroll
    for (int off = 32; off > 0; off >>= 1) {
        s += __shfl_down(s, off);
        s2 += __shfl_down(s2, off);
    }
    s = __shfl(s, 0); s2 = __shfl(s2, 0);
    float mean = s * (1.0f / CC);
    float var = s2 * (1.0f / CC) - mean * mean;
    float rstd = rsqrtf(var + 1e-5f);

    u16* dst = out + (size_t)r * CC;
#pragma unroll
    for (int k = 0; k < 6; k++) {
        int c = lane + k * 64;
        dst[c] = f2bu((xv[k] - mean) * rstd * g[c] + bta[c]);
    }
}

// ---------------------------------------------------------------------------
// K4: LN2 on residual stream -> bf16 rows
// ---------------------------------------------------------------------------
__global__ __launch_bounds__(64) void ln2_k(const float* __restrict__ xin,
                                            const float* __restrict__ g,
                                            const float* __restrict__ bta,
                                            u16* __restrict__ out, int row_off) {
    int r = blockIdx.x;
    int lane = threadIdx.x;
    const float* src = xin + (size_t)(row_off + r) * CC;
    float xv[6];
    float s = 0.f, s2 = 0.f;
#pragma unroll
    for (int k = 0; k < 6; k++) {
        float v = src[lane + k * 64];
        xv[k] = v; s += v; s2 += v * v;
    }
#pragma unroll
    for (int off = 32; off > 0; off >>= 1) {
        s += __shfl_down(s, off);
        s2 += __shfl_down(s2, off);
    }
    s = __shfl(s, 0); s2 = __shfl(s2, 0);
    float mean = s * (1.0f / CC);
    float var = s2 * (1.0f / CC) - mean * mean;
    float rstd = rsqrtf(var + 1e-5f);
    u16* dst = out + (size_t)r * CC;
#pragma unroll
    for (int k = 0; k < 6; k++) {
        int c = lane + k * 64;
        dst[c] = f2bu((xv[k] - mean) * rstd * g[c] + bta[c]);
    }
}

// ---------------------------------------------------------------------------
// K2: MFMA GEMM  C = A(MxK bf16) @ W^T(NxK bf16) + bias(f32)
// 128x128 tile, BK=32, 256 thr = 4 waves.
// Staging: global_load_lds 16B, linear LDS [128][32], XOR-swizzled 16B units.
// Block remap: bijective XCD swizzle (m204), row-panel-major logical order
// so each XCD reads a contiguous A chunk once (A-panel L2 reuse).
// ---------------------------------------------------------------------------
template <int EPI>
__global__ __launch_bounds__(256) void mgemm_k(const u16* __restrict__ A,
                                               const u16* __restrict__ Bt,
                                               const float* __restrict__ bias,
                                               u16* __restrict__ outb,
                                               int M, int Nn, int K,
                                               const float* __restrict__ resid,
                                               float* __restrict__ dout, int off_idx) {
    __shared__ u16 As[128 * 32];
    __shared__ u16 Bs[128 * 32];
    int tid = threadIdx.x;
    int lane = tid & 63, wave = tid >> 6;
    int wy = (wave >> 1) * 64, wx = (wave & 1) * 64;

    // ---- bijective XCD swizzle: contiguous row panels per XCD ----
    unsigned gx = gridDim.x;
    unsigned nwg = gx * gridDim.y;
    unsigned orig = blockIdx.y * gx + blockIdx.x;
    unsigned q = nwg >> 3, rr = nwg & 7, xcd = orig & 7;
    unsigned wgid = (xcd < rr ? xcd * (q + 1) : rr * (q + 1) + (xcd - rr) * q) + (orig >> 3);
    int row0 = (int)(wgid / gx) * 128, col0 = (int)(wgid % gx) * 128;

    int mrow = lane & 15, kq = lane >> 4;

    v4f acc[4][4];
    v4f zz = {0.f, 0.f, 0.f, 0.f};
#pragma unroll
    for (int i = 0; i < 4; i++)
#pragma unroll
        for (int j = 0; j < 4; j++) acc[i][j] = zz;

    const u16* Ab = A + (size_t)row0 * K;
    const u16* Bb = Bt + (size_t)col0 * K;

    // ---- staging precompute: 2 issues of A + 2 of B per thread per k-step ----
    int u0 = wave * 128 + lane;        // unit 0..511 (each unit = 16B)
    int u1 = u0 + 64;
    int r0 = u0 >> 2, r1 = u1 >> 2;
    int k0s = (u0 & 3) ^ ((r0 >> 1) & 3);
    int k1s = (u1 & 3) ^ ((r1 >> 1) & 3);
    const u16* gA0 = Ab + (size_t)r0 * K + 8 * k0s;
    const u16* gA1 = Ab + (size_t)r1 * K + 8 * k1s;
    const u16* gB0 = Bb + (size_t)r0 * K + 8 * k0s;
    const u16* gB1 = Bb + (size_t)r1 * K + 8 * k1s;
    u16* lA0 = &As[(size_t)wave * 1024];            // units [wave*128, +64)
    u16* lA1 = &As[(size_t)wave * 1024 + 512];      // units [wave*128+64, +64)
    u16* lB0 = &Bs[(size_t)wave * 1024];
    u16* lB1 = &Bs[(size_t)wave * 1024 + 512];

    // ---- read-side swizzled offsets (loop-invariant) ----
    int offA[4], offB[4];
#pragma unroll
    for (int i = 0; i < 4; i++) {
        int ra = wy + i * 16 + mrow;
        int rb = wx + i * 16 + mrow;
        offA[i] = (ra * 4 + (kq ^ ((ra >> 1) & 3))) * 8;
        offB[i] = (rb * 4 + (kq ^ ((rb >> 1) & 3))) * 8;
    }

    for (int kt = 0; kt < K; kt += 32) {
        gload_lds16(gA0, lA0);
        gload_lds16(gA1, lA1);
        gload_lds16(gB0, lB0);
        gload_lds16(gB1, lB1);
        gA0 += 32; gA1 += 32; gB0 += 32; gB1 += 32;
        __syncthreads();
        v8bf af[4], bfr[4];
#pragma unroll
        for (int i = 0; i < 4; i++) {
            af[i]  = *(const v8bf*)(&As[offA[i]]);
            bfr[i] = *(const v8bf*)(&Bs[offB[i]]);
        }
#pragma unroll
        for (int i = 0; i < 4; i++)
#pragma unroll
            for (int j = 0; j < 4; j++)
                acc[i][j] = __builtin_amdgcn_mfma_f32_16x16x32_bf16(af[i], bfr[j], acc[i][j], 0, 0, 0);
        __syncthreads();
    }

#pragma unroll
    for (int i = 0; i < 4; i++) {
#pragma unroll
        for (int j = 0; j < 4; j++) {
#pragma unroll
            for (int r = 0; r < 4; r++) {
                int row = row0 + wy + i * 16 + kq * 4 + r;
                int col = col0 + wx + j * 16 + mrow;
                float v = acc[i][j][r] + bias[col];
                if constexpr (EPI == 0) {
                    outb[(size_t)row * Nn + col] = f2bu(v);
                } else if constexpr (EPI == 1) {
                    outb[(size_t)row * Nn + col] = f2bu(gelu_f(v));
                } else if constexpr (EPI == 2) {
                    int wl = row / NN, n = row % NN;
                    int wg = off_idx + wl;
                    int bi = wg >> 6, w_ = wg & 63;
                    int wh = w_ >> 3, wwi = w_ & 7;
                    int i1 = n / WSZ, j1 = n % WSZ;
                    int ho = (wh * WSZ + i1 + SHIFT) % HH;
                    int wo = (wwi * WSZ + j1 + SHIFT) % WW;
                    size_t gidx = ((size_t)bi * (HH * WW) + ho * WW + wo) * CC + col;
                    dout[gidx] = resid[gidx] + v;
                } else {  // EPI 3
                    size_t gidx = (size_t)(off_idx + row) * CC + col;
                    dout[gidx] = dout[gidx] + v;
                }
            }
        }
    }
}

// ---------------------------------------------------------------------------
// K3: MFMA attention. One wave per (window, head); 4 waves / block.
// ---------------------------------------------------------------------------
#define LDP 72  // P row stride (u16): 144B, 16B-aligned
#define LDV 72  // vT row stride (u16): 144B, 16B-aligned

__global__ __launch_bounds__(256) void attn_k(const u16* __restrict__ qkv,
                                              const float* __restrict__ mbias,
                                              u16* __restrict__ xa, int win_off) {
    __shared__ u16 PsA[4][NN * LDP];       // 4 x 7056B
    __shared__ u16 vTA[4][HD * LDV];       // 4 x 4608B
    int tid = threadIdx.x;
    int wv = tid >> 6, lane = tid & 63;
    int mrow = lane & 15, kq = lane >> 4;
    int gu = blockIdx.x * 4 + wv;          // (window,head) unit
    int h = gu % HEADS;
    int wl = gu / HEADS;
    int wg = win_off + wl;
    int w_ = wg & 63, wh = w_ >> 3, wwc = w_ & 7;
    int cls = ((wh == 7) ? 1 : 0) + ((wwc == 7) ? 2 : 0);
    u16* Ps = PsA[wv];
    u16* vT = vTA[wv];
    const u16* base = qkv + (size_t)wl * NN * (3 * CC) + h * HD;

    // ---- stage V^T into LDS: vT[d][m] = V[m][d]; m in [49,64) zero-padded ----
#pragma unroll
    for (int it = 0; it < 8; it++) {
        int idx = it * 256 + lane * 4;     // covers 64 m x 32 d
        int m = idx >> 5, d = idx & 31;    // d multiple of 4
        u64 v4 = 0;
        if (m < NN) v4 = *(const u64*)(base + (size_t)m * (3 * CC) + 2 * CC + d);
        vT[(d + 0) * LDV + m] = (u16)v4;
        vT[(d + 1) * LDV + m] = (u16)(v4 >> 16);
        vT[(d + 2) * LDV + m] = (u16)(v4 >> 32);
        vT[(d + 3) * LDV + m] = (u16)(v4 >> 48);
    }

    // ---- Q,K fragments direct from global (16B aligned), rows clamped ----
    v8bf aq[4], bk[4];
#pragma unroll
    for (int i = 0; i < 4; i++) {
        int n = 16 * i + mrow;
        if (n > 48) n = 48;
        const u16* rp = base + (size_t)n * (3 * CC) + 8 * kq;
        aq[i] = *(const v8bf*)(rp);        // Q row n, d=8kq..+7
        bk[i] = *(const v8bf*)(rp + CC);   // K row n, d=8kq..+7
    }

    v4f zz = {0.f, 0.f, 0.f, 0.f};
    v4f s[4][4];
#pragma unroll
    for (int i = 0; i < 4; i++)
#pragma unroll
        for (int j = 0; j < 4; j++) s[i][j] = zz;
#pragma unroll
    for (int i = 0; i < 4; i++)
#pragma unroll
        for (int j = 0; j < 4; j++)
            s[i][j] = __builtin_amdgcn_mfma_f32_16x16x32_bf16(aq[i], bk[j], s[i][j], 0, 0, 0);

    // ---- softmax (D layout): rows n = 16i+4kq+r, cols m = 16j+mrow ----
    const float* bb = mbias + ((size_t)cls * HEADS + h) * (NN * NN);
#pragma unroll
    for (int i = 0; i < 4; i++) {
#pragma unroll
        for (int r = 0; r < 4; r++) {
            int n = 16 * i + 4 * kq + r;
            if (n < NN) {                  // uniform across the 16-lane shfl group
                const float* br = bb + n * NN;
                float v[4];
#pragma unroll
                for (int j = 0; j < 4; j++) {
                    int m = 16 * j + mrow;
                    float t = s[i][j][r] * SCALE + br[(m > 48) ? 48 : m];
                    v[j] = (m < NN) ? t : -1e30f;
                }
                float mx = fmaxf(fmaxf(v[0], v[1]), fmaxf(v[2], v[3]));
#pragma unroll
                for (int off = 1; off < 16; off <<= 1) mx = fmaxf(mx, __shfl_xor(mx, off));
                float sum = 0.f;
#pragma unroll
                for (int j = 0; j < 4; j++) { v[j] = __expf(v[j] - mx); sum += v[j]; }
#pragma unroll
                for (int off = 1; off < 16; off <<= 1) sum += __shfl_xor(sum, off);
                float inv = 1.0f / sum;
#pragma unroll
                for (int j = 0; j < 4; j++)
                    Ps[n * LDP + 16 * j + mrow] = f2bu(v[j] * inv);
            }
        }
    }

    // ---- O = P @ V : K-dim 64 (2 steps); A rows clamped to 48 ----
    v4f o[4][2];
#pragma unroll
    for (int i = 0; i < 4; i++)
#pragma unroll
        for (int j = 0; j < 2; j++) o[i][j] = zz;
#pragma unroll
    for (int kt = 0; kt < 2; kt++) {
        v8bf ap[4], bv[2];
#pragma unroll
        for (int i = 0; i < 4; i++) {
            int pr = 16 * i + mrow;
            if (pr > 48) pr = 48;
            ap[i] = *(const v8bf*)(&Ps[pr * LDP + 8 * kq + 32 * kt]);
        }
#pragma unroll
        for (int j = 0; j < 2; j++)
            bv[j] = *(const v8bf*)(&vT[(16 * j + mrow) * LDV + 8 * kq + 32 * kt]);
#pragma unroll
        for (int i = 0; i < 4; i++)
#pragma unroll
            for (int j = 0; j < 2; j++)
                o[i][j] = __builtin_amdgcn_mfma_f32_16x16x32_bf16(ap[i], bv[j], o[i][j], 0, 0, 0);
    }

    // ---- write out: row n, col d = 16j+mrow ----
    u16* orow = xa + (size_t)wl * NN * CC + h * HD;
#pragma unroll
    for (int i = 0; i < 4; i++) {
#pragma unroll
        for (int r = 0; r < 4; r++) {
            int n = 16 * i + 4 * kq + r;
            if (n < NN) {
#pragma unroll
                for (int j = 0; j < 2; j++)
                    orow[(size_t)n * CC + 16 * j + mrow] = f2bu(o[i][j][r]);
            }
        }
    }
}

// ---------------------------------------------------------------------------
extern "C" void kernel_launch(void* const* d_in, const int* in_sizes, int n_in,
                              void* d_out, int out_size, void* d_ws, size_t ws_size,
                              hipStream_t stream) {
    const float* x     = (const float*)d_in[0];
    const float* ln1g  = (const float*)d_in[1];
    const float* ln1b  = (const float*)d_in[2];
    const float* qkvw  = (const float*)d_in[3];
    const float* qkvb  = (const float*)d_in[4];
    const float* rpb   = (const float*)d_in[5];
    const float* projw = (const float*)d_in[6];
    const float* projb = (const float*)d_in[7];
    const float* ln2g  = (const float*)d_in[8];
    const float* ln2b  = (const float*)d_in[9];
    const float* fc1w  = (const float*)d_in[10];
    const float* fc1b  = (const float*)d_in[11];
    const float* fc2w  = (const float*)d_in[12];
    const float* fc2b  = (const float*)d_in[13];
    float* out = (float*)d_out;
    char* ws = (char*)d_ws;

    // ---- weight regions (bf16, transposed to NxK) + mbias (f32) ----
    size_t o = 0;
    auto walloc = [&](size_t elems) { size_t c = o; o += ((elems * 2 + 1023) & ~(size_t)1023); return c; };
    size_t o_qkvT = walloc((size_t)1152 * 384);
    size_t o_projT = walloc((size_t)384 * 384);
    size_t o_fc1T = walloc((size_t)1536 * 384);
    size_t o_fc2T = walloc((size_t)384 * 1536);
    size_t o_mbias = o;
    o += (((size_t)4 * HEADS * NN * NN * sizeof(float)) + 1023) & ~(size_t)1023;
    size_t wgt_end = (o + 1023) & ~(size_t)1023;
    u16* qkvT = (u16*)(ws + o_qkvT);
    u16* projT = (u16*)(ws + o_projT);
    u16* fc1T = (u16*)(ws + o_fc1T);
    u16* fc2T = (u16*)(ws + o_fc2T);
    float* mbias = (float*)(ws + o_mbias);

    cvtT_k<<<dim3(1152 / 32, 384 / 32), dim3(256), 0, stream>>>(qkvw, qkvT, 384, 1152);
    cvtT_k<<<dim3(384 / 32, 384 / 32), dim3(256), 0, stream>>>(projw, projT, 384, 384);
    cvtT_k<<<dim3(1536 / 32, 384 / 32), dim3(256), 0, stream>>>(fc1w, fc1T, 384, 1536);
    cvtT_k<<<dim3(384 / 32, 1536 / 32), dim3(256), 0, stream>>>(fc2w, fc2T, 1536, 384);
    mbias_k<<<dim3((4 * HEADS * NN * NN + 255) / 256), dim3(256), 0, stream>>>(rpb, mbias);

    size_t avail = (ws_size > wgt_end) ? ws_size - wgt_end : 0;

    // ---- attention chunking (bf16 bufs): bufA (ln/xa) + bufB (qkv) ----
    // start at 2 so the qkv intermediate (115 MB) stays L3-resident
    int nca = 2;
    size_t offB_a = 0;
    for (; nca <= 16; nca *= 2) {
        int Wc = NWIN_TOT / nca;
        size_t a = (size_t)Wc * NN * CC * 2;
        a = (a + 1023) & ~(size_t)1023;
        size_t b = (size_t)Wc * NN * (3 * CC) * 2;
        if (a + b <= avail) { offB_a = a; break; }
    }
    if (nca > 16) { nca = 16; offB_a = (((size_t)(NWIN_TOT / 16) * NN * CC * 2) + 1023) & ~(size_t)1023; }
    int Wc = NWIN_TOT / nca;
    int Rw = Wc * NN;  // multiple of 128 for nca in {2,4,8,16}

    for (int c = 0; c < nca; c++) {
        int woff = c * Wc;
        u16* bufA = (u16*)(ws + wgt_end);
        u16* bufB = (u16*)(ws + wgt_end + offB_a);
        ln_part_k<<<dim3(Rw), dim3(64), 0, stream>>>(x, ln1g, ln1b, bufA, woff);
        mgemm_k<0><<<dim3(1152 / 128, Rw / 128), dim3(256), 0, stream>>>(
            bufA, qkvT, qkvb, bufB, Rw, 1152, 384, nullptr, nullptr, 0);
        attn_k<<<dim3(Wc * 3), dim3(256), 0, stream>>>(bufB, mbias, bufA, woff);
        mgemm_k<2><<<dim3(384 / 128, Rw / 128), dim3(256), 0, stream>>>(
            bufA, projT, projb, nullptr, Rw, 384, 384, x, out, woff);
    }

    // ---- MLP chunking: ln2-out (Rc x 384 bf16) + m1 (Rc x 1536 bf16) ----
    // start at 2 so the m1 intermediate (154 MB) stays L3-resident
    int ncm = 2;
    size_t offB_m = 0;
    for (; ncm <= 16; ncm *= 2) {
        int Rc = ROWS_TOT / ncm;
        size_t a = (size_t)Rc * CC * 2;
        a = (a + 1023) & ~(size_t)1023;
        size_t b = (size_t)Rc * (4 * CC) * 2;
        if (a + b <= avail) { offB_m = a; break; }
    }
    if (ncm > 16) { ncm = 16; offB_m = (((size_t)(ROWS_TOT / 16) * CC * 2) + 1023) & ~(size_t)1023; }
    int Rc = ROWS_TOT / ncm;

    for (int c = 0; c < ncm; c++) {
        int roff = c * Rc;
        u16* bufA = (u16*)(ws + wgt_end);
        u16* bufB = (u16*)(ws + wgt_end + offB_m);
        ln2_k<<<dim3(Rc), dim3(64), 0, stream>>>(out, ln2g, ln2b, bufA, roff);
        mgemm_k<1><<<dim3(1536 / 128, Rc / 128), dim3(256), 0, stream>>>(
            bufA, fc1T, fc1b, bufB, Rc, 1536, 384, nullptr, nullptr, 0);
        mgemm_k<3><<<dim3(384 / 128, Rc / 128), dim3(256), 0, stream>>>(
            bufB, fc2T, fc2b, nullptr, Rc, 384, 1536, nullptr, out, roff);
    }
}